// Round 1
// baseline (243.895 us; speedup 1.0000x reference)
//
#include <hip/hip_runtime.h>

// Problem constants
#define BATCH 4
#define SEQ   2048
#define DIM   1024
#define MTOT  (BATCH * SEQ)   // 8192
#define BK    32              // k-tile depth for the legacy 128x128 core

typedef __bf16 bf16x8 __attribute__((ext_vector_type(8)));
typedef __bf16 bf16x4 __attribute__((ext_vector_type(4)));
typedef float  f32x4  __attribute__((ext_vector_type(4)));

// Async global->LDS, 16B per lane.
__device__ __forceinline__ void gl_lds16(const __bf16* g, __bf16* l) {
    __builtin_amdgcn_global_load_lds(
        (const __attribute__((address_space(1))) void*)g,
        (__attribute__((address_space(3))) void*)l,
        16, 0, 0);
}

// ---------------------------------------------------------------------------
// K0: fused fp32 -> bf16 conversion for x, Wq, Wk, Wv in ONE launch.
__global__ __launch_bounds__(256) void cvt_all_kernel(
    const float* __restrict__ x,  const float* __restrict__ w0,
    const float* __restrict__ w1, const float* __restrict__ w2,
    __bf16* __restrict__ xd, __bf16* __restrict__ d0,
    __bf16* __restrict__ d1, __bf16* __restrict__ d2)
{
    const int bid = blockIdx.x;
    const float* s;
    __bf16* d;
    int base;
    if (bid < 4096)      { s = x;  d = xd; base = bid; }
    else if (bid < 4608) { s = w0; d = d0; base = bid - 4096; }
    else if (bid < 5120) { s = w1; d = d1; base = bid - 4608; }
    else                 { s = w2; d = d2; base = bid - 5120; }
    const int i = (base * 256 + threadIdx.x) * 8;
    const float4 a = *(const float4*)(s + i);
    const float4 b = *(const float4*)(s + i + 4);
    bf16x8 o;
    o[0] = (__bf16)a.x; o[1] = (__bf16)a.y; o[2] = (__bf16)a.z; o[3] = (__bf16)a.w;
    o[4] = (__bf16)b.x; o[5] = (__bf16)b.y; o[6] = (__bf16)b.z; o[7] = (__bf16)b.w;
    *(bf16x8*)(d + i) = o;
}

// ---------------------------------------------------------------------------
// Legacy 128x128 bf16 GEMM core (m97 structure) — still used by scores/pv.
__device__ __forceinline__ void gemm_core(
    const __bf16* __restrict__ A, size_t lda,
    const __bf16* __restrict__ Bm, size_t ldb,
    int m0, int n0, int kTiles,
    __bf16* lA, __bf16* lB,
    f32x4 (&acc)[4][4])
{
    const int tid  = threadIdx.x;
    const int lane = tid & 63;
    const int wave = tid >> 6;
    const int wm = (wave >> 1) << 6;
    const int wn = (wave & 1) << 6;

#pragma unroll
    for (int i = 0; i < 4; ++i)
#pragma unroll
        for (int j = 0; j < 4; ++j)
            acc[i][j] = (f32x4){0.f, 0.f, 0.f, 0.f};

    for (int kt = 0; kt < kTiles; ++kt) {
        const int k0 = kt << 5;
        __syncthreads();
#pragma unroll
        for (int it = 0; it < 2; ++it) {
            const int f   = tid + (it << 8);
            const int row = f >> 2;
            const int col = (f & 3) << 3;
            gl_lds16(A  + (size_t)(m0 + row) * lda + (size_t)(k0 + col), lA + f * 8);
            gl_lds16(Bm + (size_t)(n0 + row) * ldb + (size_t)(k0 + col), lB + f * 8);
        }
        __syncthreads();

        bf16x8 af[4], bfr[4];
#pragma unroll
        for (int i = 0; i < 4; ++i) {
            af[i]  = *(const bf16x8*)(lA + (size_t)(wm + i * 16 + (lane & 15)) * BK + ((lane >> 4) << 3));
            bfr[i] = *(const bf16x8*)(lB + (size_t)(wn + i * 16 + (lane & 15)) * BK + ((lane >> 4) << 3));
        }
#pragma unroll
        for (int i = 0; i < 4; ++i)
#pragma unroll
            for (int j = 0; j < 4; ++j)
                acc[i][j] = __builtin_amdgcn_mfma_f32_16x16x32_bf16(af[i], bfr[j], acc[i][j], 0, 0, 0);
    }
}

// Epilogue for the legacy core (scores/pv): C-tile -> LDS scratch -> coalesced
// bf16x8 stores. expMask: store exp(val*scale), causal-masked on diag tiles.
__device__ __forceinline__ void store_tile_bf16(
    f32x4 (&acc)[4][4], __bf16* scratch, bool transpose, float scale,
    __bf16* dst, size_t ldo, size_t r0, size_t c0,
    bool expMask = false, bool diag = false)
{
    const int tid  = threadIdx.x;
    const int lane = tid & 63;
    const int wave = tid >> 6;
    const int wm = (wave >> 1) << 6, wn = (wave & 1) << 6;
    const int quad = lane >> 4;
    const int ln15 = lane & 15;

#pragma unroll
    for (int p = 0; p < 4; ++p) {
        __syncthreads();
        if (!transpose) {
            if (wm == ((p >> 1) << 6)) {
#pragma unroll
                for (int ih = 0; ih < 2; ++ih) {
                    const int i = ((p & 1) << 1) + ih;
                    const int lr = ih * 16 + quad * 4;
#pragma unroll
                    for (int j = 0; j < 4; ++j)
#pragma unroll
                        for (int r = 0; r < 4; ++r) {
                            const int lm = wm + ((p & 1) << 5) + lr + r;
                            const int ln = wn + j * 16 + ln15;
                            float v = acc[i][j][r] * scale;
                            if (expMask) {
                                v = (!diag || ln <= lm) ? __expf(v) : 0.f;
                            }
                            scratch[(lr + r) * 136 + wn + j * 16 + ln15] = (__bf16)v;
                        }
                }
            }
        } else {
            if (wn == ((p >> 1) << 6)) {
#pragma unroll
                for (int jh = 0; jh < 2; ++jh) {
                    const int j = ((p & 1) << 1) + jh;
                    const int lr = jh * 16 + ln15;
#pragma unroll
                    for (int i = 0; i < 4; ++i)
#pragma unroll
                        for (int r = 0; r < 4; ++r)
                            scratch[lr * 136 + wm + i * 16 + quad * 4 + r] =
                                (__bf16)(acc[i][j][r] * scale);
                }
            }
        }
        __syncthreads();
#pragma unroll
        for (int it = 0; it < 2; ++it) {
            const int g   = tid + (it << 8);
            const int row = g >> 4;
            const int col = (g & 15) << 3;
            *(bf16x8*)(dst + (r0 + p * 32 + row) * ldo + c0 + col) =
                *(const bf16x8*)(scratch + row * 136 + col);
        }
    }
}

// ---------------------------------------------------------------------------
// K1: QKV via the 256x256 / BK=64 8-phase pipeline (m201 template, plain HIP).
//   - 512 threads = 8 waves (2M x 4N); per-wave 128x64 output, but the wave's
//     rows/cols are GAPPED (wm*64+[0,64) U 128+wm*64+[0,64)) so that each
//     MFMA quadrant (mh,nh) touches exactly one staged A-half / B-half.
//   - LDS 128 KiB: [dbuf][A|B][half][128x64] bf16, st_16x32 XOR swizzle
//     (byte bit5 ^= bit9) applied as: linear LDS dest + pre-swizzled global
//     source in the stage, swizzled address on the ds_read (both-sides rule).
//   - Counted vmcnt: prefetch stream depth = 6 half-tiles, one vmcnt(4) per
//     K-tile (phase q3, after that phase's stage issue). Stream order per
//     tile: [B0, A1, A0, B1]; every stage lands >=1 barrier after the last
//     ds_read of the data it overwrites (ledger verified below per phase).
//   - Tail: vmcnt(0) at T==nt-2 (stream exhausted), no wait at T==nt-1.
__global__ __launch_bounds__(512, 2) void qkv_kernel(
    const __bf16* __restrict__ x,
    const __bf16* __restrict__ Wq,
    const __bf16* __restrict__ Wk,
    const __bf16* __restrict__ Wv,
    __bf16* __restrict__ Q, __bf16* __restrict__ Kb, __bf16* __restrict__ Vt)
{
    __shared__ __bf16 smem[65536];   // 128 KiB

    // 384 blocks: 3 weights x 32 m-tiles x 4 n-tiles; bijective XCD swizzle.
    const int L  = blockIdx.x;
    const int g  = (L & 7) * 48 + (L >> 3);
    const int z  = g >> 7;             // 0=Q, 1=K, 2=V
    const int rm = g & 127;
    const int m0 = (rm >> 2) << 8;     // 0..31 * 256
    const int n0 = (rm & 3) << 8;      // 0..3  * 256
    const __bf16* W = (z == 0) ? Wq : (z == 1) ? Wk : Wv;

    const int tid  = threadIdx.x;
    const int lane = tid & 63;
    const int ln15 = lane & 15;
    const int quad = lane >> 4;
    const int wave = tid >> 6;
    const int wm   = wave >> 2;        // 0..1
    const int wn   = wave & 3;         // 0..3

    // Staging addresses: LDS dest is linear (f*16B); global source col is
    // pre-swizzled so that a swizzled ds_read returns the right element.
    const int r0  = tid >> 3;                                   // 0..63
    const int cst = ((tid & 7) << 3) ^ ((r0 & 4) ? 16 : 0);     // element col
    const __bf16* Ab = x + (size_t)m0 * DIM;
    const __bf16* Bb = W + (size_t)n0 * DIM;

    // Fragment read offsets (elements) within a [128][64] half-buffer:
    //   addr = row*64 + ksub*32 + (quad*8 ^ ((row&4)?16:0)); row&4 == ln15&4.
    const int qx = (quad << 3) ^ ((ln15 & 4) ? 16 : 0);
    int aoff[4], boff[2];
#pragma unroll
    for (int i = 0; i < 4; ++i) aoff[i] = (wm * 64 + i * 16 + ln15) * 64 + qx;
#pragma unroll
    for (int j = 0; j < 2; ++j) boff[j] = (wn * 32 + j * 16 + ln15) * 64 + qx;

    f32x4 acc[8][4];
#pragma unroll
    for (int i = 0; i < 8; ++i)
#pragma unroll
        for (int j = 0; j < 4; ++j) acc[i][j] = (f32x4){0.f, 0.f, 0.f, 0.f};

    // LDS layout (elements): buf*32768 + op*16384 + half*8192.
#define STAGE_A(h, t) do {                                                    \
    const __bf16* gs_ = Ab + (size_t)((h) * 128 + r0) * DIM + ((t) << 6) + cst; \
    __bf16* ls_ = smem + (((t) & 1) * 32768 + (h) * 8192);                    \
    gl_lds16(gs_, ls_ + tid * 8);                                             \
    gl_lds16(gs_ + (size_t)64 * DIM, ls_ + tid * 8 + 4096); } while (0)
#define STAGE_B(h, t) do {                                                    \
    const __bf16* gs_ = Bb + (size_t)((h) * 128 + r0) * DIM + ((t) << 6) + cst; \
    __bf16* ls_ = smem + (((t) & 1) * 32768 + 16384 + (h) * 8192);            \
    gl_lds16(gs_, ls_ + tid * 8);                                             \
    gl_lds16(gs_ + (size_t)64 * DIM, ls_ + tid * 8 + 4096); } while (0)

    bf16x8 aF[4][2], bF[2][2];
#define LOAD_A(h) do { const __bf16* p_ = smem + cb_ * 32768 + (h) * 8192;    \
    _Pragma("unroll") for (int i_ = 0; i_ < 4; ++i_) {                        \
        aF[i_][0] = *(const bf16x8*)(p_ + aoff[i_]);                          \
        aF[i_][1] = *(const bf16x8*)(p_ + aoff[i_] + 32); } } while (0)
#define LOAD_B(h) do { const __bf16* p_ = smem + cb_ * 32768 + 16384 + (h) * 8192; \
    _Pragma("unroll") for (int j_ = 0; j_ < 2; ++j_) {                        \
        bF[j_][0] = *(const bf16x8*)(p_ + boff[j_]);                          \
        bF[j_][1] = *(const bf16x8*)(p_ + boff[j_] + 32); } } while (0)
#define MFMA_Q(mh, nh) do {                                                   \
    __builtin_amdgcn_s_setprio(1);                                            \
    _Pragma("unroll") for (int i_ = 0; i_ < 4; ++i_)                          \
    _Pragma("unroll") for (int j_ = 0; j_ < 2; ++j_) {                        \
        acc[(mh)*4+i_][(nh)*2+j_] = __builtin_amdgcn_mfma_f32_16x16x32_bf16(  \
            aF[i_][0], bF[j_][0], acc[(mh)*4+i_][(nh)*2+j_], 0, 0, 0);        \
        acc[(mh)*4+i_][(nh)*2+j_] = __builtin_amdgcn_mfma_f32_16x16x32_bf16(  \
            aF[i_][1], bF[j_][1], acc[(mh)*4+i_][(nh)*2+j_], 0, 0, 0); }      \
    __builtin_amdgcn_s_setprio(0); } while (0)

    const int nt = DIM / 64;   // 16 K-tiles

    // Prologue: stream elements e0..e5 = B0(0), A1(0), A0(0), B1(0), B0(1), A1(1)
    STAGE_B(0, 0);
    STAGE_A(1, 0);
    STAGE_A(0, 0);
    STAGE_B(1, 0);
    STAGE_B(0, 1);
    STAGE_A(1, 1);
    asm volatile("s_waitcnt vmcnt(4)" ::: "memory");   // tile 0 fully landed
    __builtin_amdgcn_s_barrier();

    for (int T = 0; T < nt; ++T) {
        const int cb_ = T & 1;
        // q0: quadrant (A0,B0); stage A0(T+1) [overwrites A0(T-1), last read q3 of T-1]
        LOAD_A(0); LOAD_B(0);
        if (T + 1 < nt) STAGE_A(0, T + 1);
        __builtin_amdgcn_s_barrier();
        MFMA_Q(0, 0);
        __builtin_amdgcn_s_barrier();
        // q1: (A1,B0) reuse bF; stage B1(T+1) [B1(T-1) last read q2 of T-1]
        LOAD_A(1);
        if (T + 1 < nt) STAGE_B(1, T + 1);
        __builtin_amdgcn_s_barrier();
        MFMA_Q(1, 0);
        __builtin_amdgcn_s_barrier();
        // q2: (A1,B1) reuse aF; stage B0(T+2) [B0(T) last read q0 — 2 phases ago]
        LOAD_B(1);
        if (T + 2 < nt) STAGE_B(0, T + 2);
        __builtin_amdgcn_s_barrier();
        MFMA_Q(1, 1);
        __builtin_amdgcn_s_barrier();
        // q3: (A0,B1) reuse bF; stage A1(T+2) [A1(T) last read q1]; counted wait
        LOAD_A(0);
        if (T + 2 < nt) {
            STAGE_A(1, T + 2);
            asm volatile("s_waitcnt vmcnt(4)" ::: "memory");   // tile T+1 landed
        } else if (T + 1 < nt) {
            asm volatile("s_waitcnt vmcnt(0)" ::: "memory");   // tail drain
        }
        __builtin_amdgcn_s_barrier();
        MFMA_Q(0, 1);
        __builtin_amdgcn_s_barrier();
    }
#undef STAGE_A
#undef STAGE_B
#undef LOAD_A
#undef LOAD_B
#undef MFMA_Q

    // ---------------- epilogue: 2 slabs of 128x256 via LDS scratch ----------
    __syncthreads();
    __bf16* scratch = smem;            // [128][264] bf16 = 67.6 KB

    if (z < 2) {
        __bf16* dst = (z == 0) ? Q : Kb;
#pragma unroll
        for (int h = 0; h < 2; ++h) {  // slab over C rows: mf in {4h..4h+3}
#pragma unroll
            for (int im = 0; im < 4; ++im) {
                const int lr = wm * 64 + im * 16 + quad * 4;
#pragma unroll
                for (int nf = 0; nf < 4; ++nf) {
                    const int lc = (nf >> 1) * 128 + wn * 32 + (nf & 1) * 16 + ln15;
#pragma unroll
                    for (int r = 0; r < 4; ++r)
                        scratch[(lr + r) * 264 + lc] = (__bf16)acc[h * 4 + im][nf][r];
                }
            }
            __syncthreads();
#pragma unroll
            for (int it = 0; it < 8; ++it) {
                const int f = tid + (it << 9);
                const int row = f >> 5, blk = f & 31;
                *(bf16x8*)(dst + (size_t)(m0 + h * 128 + row) * DIM + n0 + blk * 8) =
                    *(const bf16x8*)(scratch + row * 264 + blk * 8);
            }
            __syncthreads();
        }
    } else {
        // V transposed: Vt[b][d][s]
        const size_t b  = (size_t)(m0 >> 11);
        const int  ms0  = m0 & (SEQ - 1);
        __bf16* dst = Vt + b * (size_t)DIM * SEQ;
#pragma unroll
        for (int h = 0; h < 2; ++h) {  // slab over C cols (d): nf in {2h,2h+1}
#pragma unroll
            for (int jn = 0; jn < 2; ++jn) {
                const int lrow = wn * 32 + jn * 16 + ln15;
#pragma unroll
                for (int mf = 0; mf < 8; ++mf) {
                    const int lcol = (mf >> 2) * 128 + wm * 64 + (mf & 3) * 16 + quad * 4;
                    bf16x4 v;
#pragma unroll
                    for (int r = 0; r < 4; ++r) v[r] = (__bf16)acc[mf][h * 2 + jn][r];
                    *(bf16x4*)(scratch + lrow * 264 + lcol) = v;
                }
            }
            __syncthreads();
#pragma unroll
            for (int it = 0; it < 8; ++it) {
                const int f = tid + (it << 9);
                const int row = f >> 5, blk = f & 31;
                *(bf16x8*)(dst + (size_t)(n0 + h * 128 + row) * SEQ + ms0 + blk * 8) =
                    *(const bf16x8*)(scratch + row * 264 + blk * 8);
            }
            __syncthreads();
        }
    }
}

// ---------------------------------------------------------------------------
// K2: Sc[b] = exp( Q[b]·K[b]^T / 32 ), UNNORMALIZED, causal-masked on the
// diagonal tile. Tri-packed 544 blocks; XCD swizzle.
__global__ __launch_bounds__(256) void scores_kernel(
    const __bf16* __restrict__ Q, const __bf16* __restrict__ Kb,
    __bf16* __restrict__ Sc)
{
    const int L = blockIdx.x;
    const int g = (L & 7) * 68 + (L >> 3);   // 0..543
    const int b = g / 136;
    const int t = g - b * 136;
    int i = (int)((sqrtf(8.f * t + 1.f) - 1.f) * 0.5f);
    while ((i + 1) * (i + 2) / 2 <= t) ++i;
    while (i * (i + 1) / 2 > t) --i;
    const int j = t - i * (i + 1) / 2;

    __shared__ __bf16 smem[8192];
    __bf16* lA = smem;
    __bf16* lB = smem + 128 * BK;
    const __bf16* A  = Q  + (size_t)b * SEQ * DIM;
    const __bf16* Bm = Kb + (size_t)b * SEQ * DIM;

    f32x4 acc[4][4];
    gemm_core(A, DIM, Bm, DIM, i << 7, j << 7, DIM / BK, lA, lB, acc);

    store_tile_bf16(acc, smem, false, 0.03125f,   // 1/sqrt(1024)
                    Sc + (size_t)b * SEQ * SEQ, SEQ,
                    (size_t)(i << 7), (size_t)(j << 7),
                    /*expMask=*/true, /*diag=*/(i == j));
}

// ---------------------------------------------------------------------------
// K3: row sums of P' -> invl[row] = 1/sum.
__global__ __launch_bounds__(256) void rowsum_kernel(
    const __bf16* __restrict__ Sc, float* __restrict__ invl)
{
    const int rg = blockIdx.x;
    const int b  = rg >> 11;
    const int r  = rg & (SEQ - 1);
    const __bf16* row = Sc + ((size_t)b * SEQ + r) * SEQ;

    const int tid  = threadIdx.x;
    const int lane = tid & 63;
    const int wv   = tid >> 6;
    const int width = ((r >> 7) + 1) << 7;
    const int c0 = tid << 3;

    float s = 0.f;
    if (c0 < width) {
        const bf16x8 in = *(const bf16x8*)(row + c0);
#pragma unroll
        for (int k = 0; k < 8; ++k) s += (float)in[k];
    }
#pragma unroll
    for (int off = 32; off > 0; off >>= 1)
        s += __shfl_xor(s, off);

    __shared__ float red[4];
    if (lane == 0) red[wv] = s;
    __syncthreads();
    if (tid == 0)
        invl[rg] = 1.f / (red[0] + red[1] + red[2] + red[3]);
}

// ---------------------------------------------------------------------------
// K4: O[b] = (P'[b] @ V[b]) * invl, k-tiles to the causal diagonal, fp32 out.
__global__ __launch_bounds__(256) void pv_kernel(
    const __bf16* __restrict__ P, const __bf16* __restrict__ Vt,
    const float* __restrict__ invl, float* __restrict__ out)
{
    const int L = blockIdx.x;
    const int c = L & 7;
    const int k = L >> 3;                 // 0..63
    const int b = c >> 1;
    const int i = 15 - (c & 1) - ((k >> 3) << 1);   // 15,13,..,1 or 14,12,..,0
    const int x = k & 7;

    __shared__ __bf16 smem[8192];
    __bf16* lA = smem;
    __bf16* lB = smem + 128 * BK;
    const __bf16* A  = P  + (size_t)b * SEQ * SEQ;
    const __bf16* Bm = Vt + (size_t)b * DIM * SEQ;

    f32x4 acc[4][4];
    gemm_core(A, SEQ, Bm, SEQ, i << 7, x << 7, (i + 1) * (128 / BK), lA, lB, acc);

    const int lane = threadIdx.x & 63;
    const int wave = threadIdx.x >> 6;
    const int wm = (wave >> 1) << 6, wn = (wave & 1) << 6;
#pragma unroll
    for (int ii = 0; ii < 4; ++ii)
#pragma unroll
        for (int jj = 0; jj < 4; ++jj)
#pragma unroll
            for (int r = 0; r < 4; ++r) {
                const int m = (i << 7) + wm + ii * 16 + ((lane >> 4) << 2) + r;
                const int n = (x << 7) + wn + jj * 16 + (lane & 15);
                out[((size_t)b * SEQ + m) * DIM + n] =
                    acc[ii][jj][r] * invl[(b << 11) + m];
            }
}

// ---------------------------------------------------------------------------
extern "C" void kernel_launch(void* const* d_in, const int* in_sizes, int n_in,
                              void* d_out, int out_size, void* d_ws, size_t ws_size,
                              hipStream_t stream) {
    const float* x  = (const float*)d_in[0];   // fp32 per reference
    const float* Wq = (const float*)d_in[1];
    const float* Wk = (const float*)d_in[2];
    const float* Wv = (const float*)d_in[3];
    float* out = (float*)d_out;                // fp32 output (reference dtype)

    char* ws = (char*)d_ws;
    __bf16* Q  = (__bf16*)(ws);                       // 16 MB
    __bf16* Kb = (__bf16*)(ws + (16ull << 20));       // 16 MB
    __bf16* Vt = (__bf16*)(ws + (32ull << 20));       // 16 MB
    __bf16* Sc = (__bf16*)(ws + (48ull << 20));       // 32 MB bf16 exp-scores
    __bf16* Wqb = (__bf16*)(ws + (80ull << 20));      // 2 MB
    __bf16* Wkb = (__bf16*)(ws + (82ull << 20));      // 2 MB
    __bf16* Wvb = (__bf16*)(ws + (84ull << 20));      // 2 MB
    float*  invl = (float*)(ws + (86ull << 20));      // 32 KB
    // bf16 x copy lives in d_out (32 MB fp32): dead before pv writes out.
    __bf16* xb  = (__bf16*)d_out;                     // 16 MB

    cvt_all_kernel<<<dim3(5632), 256, 0, stream>>>(x, Wq, Wk, Wv, xb, Wqb, Wkb, Wvb);

    qkv_kernel    <<<dim3(384),  512, 0, stream>>>(xb, Wqb, Wkb, Wvb, Q, Kb, Vt);
    scores_kernel <<<dim3(544),  256, 0, stream>>>(Q, Kb, Sc);
    rowsum_kernel <<<dim3(MTOT), 256, 0, stream>>>(Sc, invl);
    pv_kernel     <<<dim3(512),  256, 0, stream>>>(Sc, Vt, invl, out);
}

// Round 2
// 230.272 us; speedup vs baseline: 1.0592x; 1.0592x over previous
//
#include <hip/hip_runtime.h>

// Problem constants
#define BATCH 4
#define SEQ   2048
#define DIM   1024
#define MTOT  (BATCH * SEQ)   // 8192
#define BK    32              // k-tile depth for the legacy 128x128 core

typedef __bf16 bf16x8 __attribute__((ext_vector_type(8)));
typedef __bf16 bf16x4 __attribute__((ext_vector_type(4)));
typedef float  f32x4  __attribute__((ext_vector_type(4)));

// Async global->LDS, 16B per lane.
__device__ __forceinline__ void gl_lds16(const __bf16* g, __bf16* l) {
    __builtin_amdgcn_global_load_lds(
        (const __attribute__((address_space(1))) void*)g,
        (__attribute__((address_space(3))) void*)l,
        16, 0, 0);
}

// ---------------------------------------------------------------------------
// K0: fused fp32 -> bf16 conversion for x, Wq, Wk, Wv in ONE launch.
__global__ __launch_bounds__(256) void cvt_all_kernel(
    const float* __restrict__ x,  const float* __restrict__ w0,
    const float* __restrict__ w1, const float* __restrict__ w2,
    __bf16* __restrict__ xd, __bf16* __restrict__ d0,
    __bf16* __restrict__ d1, __bf16* __restrict__ d2)
{
    const int bid = blockIdx.x;
    const float* s;
    __bf16* d;
    int base;
    if (bid < 4096)      { s = x;  d = xd; base = bid; }
    else if (bid < 4608) { s = w0; d = d0; base = bid - 4096; }
    else if (bid < 5120) { s = w1; d = d1; base = bid - 4608; }
    else                 { s = w2; d = d2; base = bid - 5120; }
    const int i = (base * 256 + threadIdx.x) * 8;
    const float4 a = *(const float4*)(s + i);
    const float4 b = *(const float4*)(s + i + 4);
    bf16x8 o;
    o[0] = (__bf16)a.x; o[1] = (__bf16)a.y; o[2] = (__bf16)a.z; o[3] = (__bf16)a.w;
    o[4] = (__bf16)b.x; o[5] = (__bf16)b.y; o[6] = (__bf16)b.z; o[7] = (__bf16)b.w;
    *(bf16x8*)(d + i) = o;
}

// ---------------------------------------------------------------------------
// Legacy 128x128 bf16 GEMM core (m97 structure) — still used by scores/pv.
__device__ __forceinline__ void gemm_core(
    const __bf16* __restrict__ A, size_t lda,
    const __bf16* __restrict__ Bm, size_t ldb,
    int m0, int n0, int kTiles,
    __bf16* lA, __bf16* lB,
    f32x4 (&acc)[4][4])
{
    const int tid  = threadIdx.x;
    const int lane = tid & 63;
    const int wave = tid >> 6;
    const int wm = (wave >> 1) << 6;
    const int wn = (wave & 1) << 6;

#pragma unroll
    for (int i = 0; i < 4; ++i)
#pragma unroll
        for (int j = 0; j < 4; ++j)
            acc[i][j] = (f32x4){0.f, 0.f, 0.f, 0.f};

    for (int kt = 0; kt < kTiles; ++kt) {
        const int k0 = kt << 5;
        __syncthreads();
#pragma unroll
        for (int it = 0; it < 2; ++it) {
            const int f   = tid + (it << 8);
            const int row = f >> 2;
            const int col = (f & 3) << 3;
            gl_lds16(A  + (size_t)(m0 + row) * lda + (size_t)(k0 + col), lA + f * 8);
            gl_lds16(Bm + (size_t)(n0 + row) * ldb + (size_t)(k0 + col), lB + f * 8);
        }
        __syncthreads();

        bf16x8 af[4], bfr[4];
#pragma unroll
        for (int i = 0; i < 4; ++i) {
            af[i]  = *(const bf16x8*)(lA + (size_t)(wm + i * 16 + (lane & 15)) * BK + ((lane >> 4) << 3));
            bfr[i] = *(const bf16x8*)(lB + (size_t)(wn + i * 16 + (lane & 15)) * BK + ((lane >> 4) << 3));
        }
#pragma unroll
        for (int i = 0; i < 4; ++i)
#pragma unroll
            for (int j = 0; j < 4; ++j)
                acc[i][j] = __builtin_amdgcn_mfma_f32_16x16x32_bf16(af[i], bfr[j], acc[i][j], 0, 0, 0);
    }
}

// Epilogue for the legacy core (scores/pv): C-tile -> LDS scratch -> coalesced
// bf16x8 stores. expMask: store exp(val*scale), causal-masked on diag tiles.
__device__ __forceinline__ void store_tile_bf16(
    f32x4 (&acc)[4][4], __bf16* scratch, bool transpose, float scale,
    __bf16* dst, size_t ldo, size_t r0, size_t c0,
    bool expMask = false, bool diag = false)
{
    const int tid  = threadIdx.x;
    const int lane = tid & 63;
    const int wave = tid >> 6;
    const int wm = (wave >> 1) << 6, wn = (wave & 1) << 6;
    const int quad = lane >> 4;
    const int ln15 = lane & 15;

#pragma unroll
    for (int p = 0; p < 4; ++p) {
        __syncthreads();
        if (!transpose) {
            if (wm == ((p >> 1) << 6)) {
#pragma unroll
                for (int ih = 0; ih < 2; ++ih) {
                    const int i = ((p & 1) << 1) + ih;
                    const int lr = ih * 16 + quad * 4;
#pragma unroll
                    for (int j = 0; j < 4; ++j)
#pragma unroll
                        for (int r = 0; r < 4; ++r) {
                            const int lm = wm + ((p & 1) << 5) + lr + r;
                            const int ln = wn + j * 16 + ln15;
                            float v = acc[i][j][r] * scale;
                            if (expMask) {
                                v = (!diag || ln <= lm) ? __expf(v) : 0.f;
                            }
                            scratch[(lr + r) * 136 + wn + j * 16 + ln15] = (__bf16)v;
                        }
                }
            }
        } else {
            if (wn == ((p >> 1) << 6)) {
#pragma unroll
                for (int jh = 0; jh < 2; ++jh) {
                    const int j = ((p & 1) << 1) + jh;
                    const int lr = jh * 16 + ln15;
#pragma unroll
                    for (int i = 0; i < 4; ++i)
#pragma unroll
                        for (int r = 0; r < 4; ++r)
                            scratch[lr * 136 + wm + i * 16 + quad * 4 + r] =
                                (__bf16)(acc[i][j][r] * scale);
                }
            }
        }
        __syncthreads();
#pragma unroll
        for (int it = 0; it < 2; ++it) {
            const int g   = tid + (it << 8);
            const int row = g >> 4;
            const int col = (g & 15) << 3;
            *(bf16x8*)(dst + (r0 + p * 32 + row) * ldo + c0 + col) =
                *(const bf16x8*)(scratch + row * 136 + col);
        }
    }
}

// ---------------------------------------------------------------------------
// K1: QKV via the 256x256 / BK=64 8-phase pipeline.
//   v2 changes vs round 1:
//   - Rotation swizzle designed for the actual ds_read pattern: phys 8-elem
//     chunk = (logical_chunk + (row&7)) & 7. Per ds_read_b128, each 16-lane
//     group covers all 8 16B column slots (2 lanes/slot = free; 4-way/32
//     lanes = b128 minimum). Inverse rotation pre-applied to the
//     global_load_lds SOURCE column; forward rotation on the ds_read address
//     (both-sides rule, m104/m231).
//   - Quadrant order (0,0)->(0,1)->(1,1)->(1,0), holding the B0 fragments in
//     registers across the tile: ds_read volume 32 KB -> 24 KB per K-tile per
//     wave; q3 has no ds_read (ideal vmcnt placement).
//   - Stage ledger (depth 6 half-tiles, FIFO): B1(T+1)@q0, A1(T+1)@q1,
//     A0(T+2)@q2, B0(T+2)@q3 + vmcnt(4). Every stage lands >=2 barriers after
//     the last ds_read of the slot it overwrites (A0/B0 slots die at q0).
__global__ __launch_bounds__(512, 2) void qkv_kernel(
    const __bf16* __restrict__ x,
    const __bf16* __restrict__ Wq,
    const __bf16* __restrict__ Wk,
    const __bf16* __restrict__ Wv,
    __bf16* __restrict__ Q, __bf16* __restrict__ Kb, __bf16* __restrict__ Vt)
{
    __shared__ __bf16 smem[65536];   // 128 KiB

    // 384 blocks: 3 weights x 32 m-tiles x 4 n-tiles; bijective XCD swizzle.
    const int L  = blockIdx.x;
    const int g  = (L & 7) * 48 + (L >> 3);
    const int z  = g >> 7;             // 0=Q, 1=K, 2=V
    const int rm = g & 127;
    const int m0 = (rm >> 2) << 8;     // 0..31 * 256
    const int n0 = (rm & 3) << 8;      // 0..3  * 256
    const __bf16* W = (z == 0) ? Wq : (z == 1) ? Wk : Wv;

    const int tid  = threadIdx.x;
    const int lane = tid & 63;
    const int ln15 = lane & 15;
    const int quad = lane >> 4;
    const int wave = tid >> 6;
    const int wm   = wave >> 2;        // 0..1
    const int wn   = wave & 3;         // 0..3

    // Staging: LDS dest linear (lane*16B); global source column carries the
    // INVERSE rotation so the rotated ds_read returns the right element.
    const int r0  = tid >> 3;                                   // dest row 0..63
    const int cst = ((((tid & 7) + 8) - (r0 & 7)) & 7) << 3;    // element col
    const __bf16* Ab = x + (size_t)m0 * DIM;
    const __bf16* Bb = W + (size_t)n0 * DIM;

    // Fragment read offsets within a [128][64] half-buffer:
    //   phys elem col = (ksub*32 + quad*8 + (row&7)*8) & 63 ; row&7 == ln15&7.
    //   ksub1 address = ksub0 address ^ 32 (chunk+4 mod 8).
    const int cq = (((quad << 3) + ((ln15 & 7) << 3)) & 63);
    int aoff[4], boff[2];
#pragma unroll
    for (int i = 0; i < 4; ++i) aoff[i] = (wm * 64 + i * 16 + ln15) * 64 + cq;
#pragma unroll
    for (int j = 0; j < 2; ++j) boff[j] = (wn * 32 + j * 16 + ln15) * 64 + cq;

    f32x4 acc[8][4];
#pragma unroll
    for (int i = 0; i < 8; ++i)
#pragma unroll
        for (int j = 0; j < 4; ++j) acc[i][j] = (f32x4){0.f, 0.f, 0.f, 0.f};

    // LDS layout (elements): buf*32768 + op*16384 + half*8192.
#define STAGE_A(h, t) do {                                                    \
    const __bf16* gs_ = Ab + (size_t)((h) * 128 + r0) * DIM + ((t) << 6) + cst; \
    __bf16* ls_ = smem + (((t) & 1) * 32768 + (h) * 8192);                    \
    gl_lds16(gs_, ls_ + tid * 8);                                             \
    gl_lds16(gs_ + (size_t)64 * DIM, ls_ + tid * 8 + 4096); } while (0)
#define STAGE_B(h, t) do {                                                    \
    const __bf16* gs_ = Bb + (size_t)((h) * 128 + r0) * DIM + ((t) << 6) + cst; \
    __bf16* ls_ = smem + (((t) & 1) * 32768 + 16384 + (h) * 8192);            \
    gl_lds16(gs_, ls_ + tid * 8);                                             \
    gl_lds16(gs_ + (size_t)64 * DIM, ls_ + tid * 8 + 4096); } while (0)

    bf16x8 aF[4][2], bF[2][2][2];   // bF[set][j][ksub]; set0 = B-half0 persists
#define LOAD_A(h) do { const __bf16* p_ = smem + cb_ * 32768 + (h) * 8192;    \
    _Pragma("unroll") for (int i_ = 0; i_ < 4; ++i_) {                        \
        aF[i_][0] = *(const bf16x8*)(p_ + aoff[i_]);                          \
        aF[i_][1] = *(const bf16x8*)(p_ + (aoff[i_] ^ 32)); } } while (0)
#define LOAD_B(s, h) do { const __bf16* p_ = smem + cb_ * 32768 + 16384 + (h) * 8192; \
    _Pragma("unroll") for (int j_ = 0; j_ < 2; ++j_) {                        \
        bF[s][j_][0] = *(const bf16x8*)(p_ + boff[j_]);                       \
        bF[s][j_][1] = *(const bf16x8*)(p_ + (boff[j_] ^ 32)); } } while (0)
#define MFMA_Q(mh, nh, s) do {                                                \
    __builtin_amdgcn_s_setprio(1);                                            \
    _Pragma("unroll") for (int i_ = 0; i_ < 4; ++i_)                          \
    _Pragma("unroll") for (int j_ = 0; j_ < 2; ++j_) {                        \
        acc[(mh)*4+i_][(nh)*2+j_] = __builtin_amdgcn_mfma_f32_16x16x32_bf16(  \
            aF[i_][0], bF[s][j_][0], acc[(mh)*4+i_][(nh)*2+j_], 0, 0, 0);     \
        acc[(mh)*4+i_][(nh)*2+j_] = __builtin_amdgcn_mfma_f32_16x16x32_bf16(  \
            aF[i_][1], bF[s][j_][1], acc[(mh)*4+i_][(nh)*2+j_], 0, 0, 0); }   \
    __builtin_amdgcn_s_setprio(0); } while (0)

    const int nt = DIM / 64;   // 16 K-tiles

    // Prologue stream (FIFO): A0(0),B0(0),B1(0),A1(0),A0(1),B0(1).
    STAGE_A(0, 0);
    STAGE_B(0, 0);
    STAGE_B(1, 0);
    STAGE_A(1, 0);
    STAGE_A(0, 1);
    STAGE_B(0, 1);
    asm volatile("s_waitcnt vmcnt(4)" ::: "memory");   // tile 0 fully landed
    __builtin_amdgcn_s_barrier();

    for (int T = 0; T < nt; ++T) {
        const int cb_ = T & 1;
        // q0: (A0,B0->set0); stage B1(T+1) [B1(T-1) last read q1(T-1)]
        LOAD_A(0); LOAD_B(0, 0);
        if (T + 1 < nt) STAGE_B(1, T + 1);
        __builtin_amdgcn_s_barrier();
        MFMA_Q(0, 0, 0);
        __builtin_amdgcn_s_barrier();
        // q1: (A0,B1->set1); stage A1(T+1) [A1(T-1) last read q2(T-1)]
        LOAD_B(1, 1);
        if (T + 1 < nt) STAGE_A(1, T + 1);
        __builtin_amdgcn_s_barrier();
        MFMA_Q(0, 1, 1);
        __builtin_amdgcn_s_barrier();
        // q2: (A1,B1 regs); stage A0(T+2) [A0(T) slot last read q0(T)]
        LOAD_A(1);
        if (T + 2 < nt) STAGE_A(0, T + 2);
        __builtin_amdgcn_s_barrier();
        MFMA_Q(1, 1, 1);
        __builtin_amdgcn_s_barrier();
        // q3: (A1,B0 regs) — NO ds_read; stage B0(T+2); counted wait
        if (T + 2 < nt) {
            STAGE_B(0, T + 2);
            asm volatile("s_waitcnt vmcnt(4)" ::: "memory");   // tile T+1 landed
        } else if (T + 1 < nt) {
            asm volatile("s_waitcnt vmcnt(0)" ::: "memory");   // tail drain
        }
        __builtin_amdgcn_s_barrier();
        MFMA_Q(1, 0, 0);
        __builtin_amdgcn_s_barrier();
    }
#undef STAGE_A
#undef STAGE_B
#undef LOAD_A
#undef LOAD_B
#undef MFMA_Q

    // ---------------- epilogue: 2 slabs of 128x256 via LDS scratch ----------
    __syncthreads();
    __bf16* scratch = smem;            // [128][264] bf16 = 67.6 KB

    if (z < 2) {
        __bf16* dst = (z == 0) ? Q : Kb;
#pragma unroll
        for (int h = 0; h < 2; ++h) {  // slab over C rows: mf in {4h..4h+3}
#pragma unroll
            for (int im = 0; im < 4; ++im) {
                const int lr = wm * 64 + im * 16 + quad * 4;
#pragma unroll
                for (int nf = 0; nf < 4; ++nf) {
                    const int lc = (nf >> 1) * 128 + wn * 32 + (nf & 1) * 16 + ln15;
#pragma unroll
                    for (int r = 0; r < 4; ++r)
                        scratch[(lr + r) * 264 + lc] = (__bf16)acc[h * 4 + im][nf][r];
                }
            }
            __syncthreads();
#pragma unroll
            for (int it = 0; it < 8; ++it) {
                const int f = tid + (it << 9);
                const int row = f >> 5, blk = f & 31;
                *(bf16x8*)(dst + (size_t)(m0 + h * 128 + row) * DIM + n0 + blk * 8) =
                    *(const bf16x8*)(scratch + row * 264 + blk * 8);
            }
            __syncthreads();
        }
    } else {
        // V transposed: Vt[b][d][s]
        const size_t b  = (size_t)(m0 >> 11);
        const int  ms0  = m0 & (SEQ - 1);
        __bf16* dst = Vt + b * (size_t)DIM * SEQ;
#pragma unroll
        for (int h = 0; h < 2; ++h) {  // slab over C cols (d): nf in {2h,2h+1}
#pragma unroll
            for (int jn = 0; jn < 2; ++jn) {
                const int lrow = wn * 32 + jn * 16 + ln15;
#pragma unroll
                for (int mf = 0; mf < 8; ++mf) {
                    const int lcol = (mf >> 2) * 128 + wm * 64 + (mf & 3) * 16 + quad * 4;
                    bf16x4 v;
#pragma unroll
                    for (int r = 0; r < 4; ++r) v[r] = (__bf16)acc[mf][h * 2 + jn][r];
                    *(bf16x4*)(scratch + lrow * 264 + lcol) = v;
                }
            }
            __syncthreads();
#pragma unroll
            for (int it = 0; it < 8; ++it) {
                const int f = tid + (it << 9);
                const int row = f >> 5, blk = f & 31;
                *(bf16x8*)(dst + (size_t)(n0 + h * 128 + row) * SEQ + ms0 + blk * 8) =
                    *(const bf16x8*)(scratch + row * 264 + blk * 8);
            }
            __syncthreads();
        }
    }
}

// ---------------------------------------------------------------------------
// K2: Sc[b] = exp( Q[b]·K[b]^T / 32 ), UNNORMALIZED, causal-masked on the
// diagonal tile. Tri-packed 544 blocks; XCD swizzle.
__global__ __launch_bounds__(256) void scores_kernel(
    const __bf16* __restrict__ Q, const __bf16* __restrict__ Kb,
    __bf16* __restrict__ Sc)
{
    const int L = blockIdx.x;
    const int g = (L & 7) * 68 + (L >> 3);   // 0..543
    const int b = g / 136;
    const int t = g - b * 136;
    int i = (int)((sqrtf(8.f * t + 1.f) - 1.f) * 0.5f);
    while ((i + 1) * (i + 2) / 2 <= t) ++i;
    while (i * (i + 1) / 2 > t) --i;
    const int j = t - i * (i + 1) / 2;

    __shared__ __bf16 smem[8192];
    __bf16* lA = smem;
    __bf16* lB = smem + 128 * BK;
    const __bf16* A  = Q  + (size_t)b * SEQ * DIM;
    const __bf16* Bm = Kb + (size_t)b * SEQ * DIM;

    f32x4 acc[4][4];
    gemm_core(A, DIM, Bm, DIM, i << 7, j << 7, DIM / BK, lA, lB, acc);

    store_tile_bf16(acc, smem, false, 0.03125f,   // 1/sqrt(1024)
                    Sc + (size_t)b * SEQ * SEQ, SEQ,
                    (size_t)(i << 7), (size_t)(j << 7),
                    /*expMask=*/true, /*diag=*/(i == j));
}

// ---------------------------------------------------------------------------
// K3: row sums of P' -> invl[row] = 1/sum. 2048 blocks, one row per wave
// (8192 tiny blocks were dispatch-rate-limited).
__global__ __launch_bounds__(256) void rowsum_kernel(
    const __bf16* __restrict__ Sc, float* __restrict__ invl)
{
    const int tid  = threadIdx.x;
    const int lane = tid & 63;
    const int wv   = tid >> 6;
    const int rg   = blockIdx.x * 4 + wv;
    const int b    = rg >> 11;
    const int r    = rg & (SEQ - 1);
    const __bf16* row = Sc + ((size_t)b * SEQ + r) * SEQ;
    const int width = ((r >> 7) + 1) << 7;   // multiple of 128

    float s = 0.f;
    for (int c0 = lane << 3; c0 < width; c0 += 512) {
        const bf16x8 in = *(const bf16x8*)(row + c0);
#pragma unroll
        for (int k = 0; k < 8; ++k) s += (float)in[k];
    }
#pragma unroll
    for (int off = 32; off > 0; off >>= 1)
        s += __shfl_xor(s, off);
    if (lane == 0)
        invl[rg] = 1.f / s;
}

// ---------------------------------------------------------------------------
// K4: O[b] = (P'[b] @ V[b]) * invl, k-tiles to the causal diagonal, fp32 out.
__global__ __launch_bounds__(256) void pv_kernel(
    const __bf16* __restrict__ P, const __bf16* __restrict__ Vt,
    const float* __restrict__ invl, float* __restrict__ out)
{
    const int L = blockIdx.x;
    const int c = L & 7;
    const int k = L >> 3;                 // 0..63
    const int b = c >> 1;
    const int i = 15 - (c & 1) - ((k >> 3) << 1);   // 15,13,..,1 or 14,12,..,0
    const int x = k & 7;

    __shared__ __bf16 smem[8192];
    __bf16* lA = smem;
    __bf16* lB = smem + 128 * BK;
    const __bf16* A  = P  + (size_t)b * SEQ * SEQ;
    const __bf16* Bm = Vt + (size_t)b * DIM * SEQ;

    f32x4 acc[4][4];
    gemm_core(A, SEQ, Bm, SEQ, i << 7, x << 7, (i + 1) * (128 / BK), lA, lB, acc);

    const int lane = threadIdx.x & 63;
    const int wave = threadIdx.x >> 6;
    const int wm = (wave >> 1) << 6, wn = (wave & 1) << 6;
#pragma unroll
    for (int ii = 0; ii < 4; ++ii)
#pragma unroll
        for (int jj = 0; jj < 4; ++jj)
#pragma unroll
            for (int r = 0; r < 4; ++r) {
                const int m = (i << 7) + wm + ii * 16 + ((lane >> 4) << 2) + r;
                const int n = (x << 7) + wn + jj * 16 + (lane & 15);
                out[((size_t)b * SEQ + m) * DIM + n] =
                    acc[ii][jj][r] * invl[(b << 11) + m];
            }
}

// ---------------------------------------------------------------------------
extern "C" void kernel_launch(void* const* d_in, const int* in_sizes, int n_in,
                              void* d_out, int out_size, void* d_ws, size_t ws_size,
                              hipStream_t stream) {
    const float* x  = (const float*)d_in[0];   // fp32 per reference
    const float* Wq = (const float*)d_in[1];
    const float* Wk = (const float*)d_in[2];
    const float* Wv = (const float*)d_in[3];
    float* out = (float*)d_out;                // fp32 output (reference dtype)

    char* ws = (char*)d_ws;
    __bf16* Q  = (__bf16*)(ws);                       // 16 MB
    __bf16* Kb = (__bf16*)(ws + (16ull << 20));       // 16 MB
    __bf16* Vt = (__bf16*)(ws + (32ull << 20));       // 16 MB
    __bf16* Sc = (__bf16*)(ws + (48ull << 20));       // 32 MB bf16 exp-scores
    __bf16* Wqb = (__bf16*)(ws + (80ull << 20));      // 2 MB
    __bf16* Wkb = (__bf16*)(ws + (82ull << 20));      // 2 MB
    __bf16* Wvb = (__bf16*)(ws + (84ull << 20));      // 2 MB
    float*  invl = (float*)(ws + (86ull << 20));      // 32 KB
    // bf16 x copy lives in d_out (32 MB fp32): dead before pv writes out.
    __bf16* xb  = (__bf16*)d_out;                     // 16 MB

    cvt_all_kernel<<<dim3(5632), 256, 0, stream>>>(x, Wq, Wk, Wv, xb, Wqb, Wkb, Wvb);

    qkv_kernel    <<<dim3(384),  512, 0, stream>>>(xb, Wqb, Wkb, Wvb, Q, Kb, Vt);
    scores_kernel <<<dim3(544),  256, 0, stream>>>(Q, Kb, Sc);
    rowsum_kernel <<<dim3(2048), 256, 0, stream>>>(Sc, invl);
    pv_kernel     <<<dim3(512),  256, 0, stream>>>(Sc, Vt, invl, out);
}